// Round 6
// baseline (601.025 us; speedup 1.0000x reference)
//
#include <hip/hip_runtime.h>
#include <math.h>

// ---------------------------------------------------------------------------
// ARMA GNN forward: gcn_norm -> ARMAConv(128->32,K=2,T=2,relu) -> relu ->
//                   ARMAConv(32->40,K=2,T=2) -> log_softmax
// CSC gather propagation (no atomics); dual-chain gathers for MLP;
// node-batched LDS-weight GEMMs (4x fewer ds_reads).
// ---------------------------------------------------------------------------

__global__ void k_hist(const int* __restrict__ col, int* __restrict__ deg, int e) {
    int i = blockIdx.x * blockDim.x + threadIdx.x;
    if (i < e) atomicAdd(&deg[col[i]], 1);
}

__global__ void k_dinv(const int* __restrict__ deg, float* __restrict__ dinv, int n) {
    int i = blockIdx.x * blockDim.x + threadIdx.x;
    if (i < n) {
        int d = deg[i];
        dinv[i] = d > 0 ? rsqrtf((float)d) : 0.0f;
    }
}

__global__ void k_scan1(const int* __restrict__ deg, int* __restrict__ start,
                        int* __restrict__ bsum, int n) {
    __shared__ int s[256];
    int t = threadIdx.x, idx = blockIdx.x * 256 + t;
    int v = (idx < n) ? deg[idx] : 0;
    s[t] = v; __syncthreads();
    for (int o = 1; o < 256; o <<= 1) {
        int x = (t >= o) ? s[t - o] : 0;
        __syncthreads(); s[t] += x; __syncthreads();
    }
    if (idx <= n) start[idx] = s[t] - v;
    if (t == 255) bsum[blockIdx.x] = s[255];
}

__global__ void k_scan2(const int* __restrict__ bsum, int* __restrict__ bscan) {
    __shared__ int s[256];
    int t = threadIdx.x;
    int v = bsum[t]; s[t] = v; __syncthreads();
    for (int o = 1; o < 256; o <<= 1) {
        int x = (t >= o) ? s[t - o] : 0;
        __syncthreads(); s[t] += x; __syncthreads();
    }
    bscan[t] = s[t] - v;
}

__global__ void k_scan3(int* __restrict__ start, int* __restrict__ cursor,
                        const int* __restrict__ bscan, int n) {
    int idx = blockIdx.x * 256 + threadIdx.x;
    if (idx <= n) {
        int v = start[idx] + bscan[idx >> 8];
        start[idx] = v;
        if (idx < n) cursor[idx] = v;
    }
}

__global__ void k_sort(const int* __restrict__ row, const int* __restrict__ col,
                       const float* __restrict__ dinv, int* __restrict__ cursor,
                       int2* __restrict__ sedge, int e) {
    int i = blockIdx.x * blockDim.x + threadIdx.x;
    if (i < e) {
        int r = row[i], c = col[i];
        int pos = atomicAdd(&cursor[c], 1);
        sedge[pos] = make_int2(r, __float_as_int(dinv[r] * dinv[c]));
    }
}

// ---- fused init+root GEMM, NPW nodes per thread (amortizes LDS reads) ------
// requires n % NPW == 0 and F_IN % 4 == 0
template<int F_IN, int F_OUT, int K, int GPB, int NPW>
__global__ void k_gemm_in(const float* __restrict__ x,
                          const float* __restrict__ w_init,
                          const float* __restrict__ w_root,
                          float* __restrict__ out0,
                          float* __restrict__ root,
                          int n) {
    constexpr int KF = K * F_OUT;
    constexpr int WSZ = K * F_IN * F_OUT;
    __shared__ float ws_i[WSZ];
    __shared__ float ws_r[WSZ];
    int t = threadIdx.x;
    for (int i = t; i < WSZ; i += blockDim.x) {
        ws_i[i] = w_init[i];
        ws_r[i] = w_root[i];
    }
    __syncthreads();
    int g  = t / KF;
    int kf = t % KF;
    int k  = kf / F_OUT;
    int h  = kf % F_OUT;
    long node0 = ((long)blockIdx.x * GPB + g) * NPW;
    if (node0 >= n) return;                 // n % NPW == 0 -> all NPW valid
    const float* wip = ws_i + k * F_IN * F_OUT + h;
    const float* wrp = ws_r + k * F_IN * F_OUT + h;
    float ai[NPW], ar[NPW];
#pragma unroll
    for (int j = 0; j < NPW; ++j) { ai[j] = 0.0f; ar[j] = 0.0f; }
    for (int f = 0; f < F_IN; f += 4) {
        float wi0 = wip[(f + 0) * F_OUT], wi1 = wip[(f + 1) * F_OUT];
        float wi2 = wip[(f + 2) * F_OUT], wi3 = wip[(f + 3) * F_OUT];
        float wr0 = wrp[(f + 0) * F_OUT], wr1 = wrp[(f + 1) * F_OUT];
        float wr2 = wrp[(f + 2) * F_OUT], wr3 = wrp[(f + 3) * F_OUT];
#pragma unroll
        for (int j = 0; j < NPW; ++j) {
            float4 xv = *(const float4*)&x[(node0 + j) * F_IN + f];
            ai[j] = fmaf(xv.w, wi3, fmaf(xv.z, wi2, fmaf(xv.y, wi1, fmaf(xv.x, wi0, ai[j]))));
            ar[j] = fmaf(xv.w, wr3, fmaf(xv.z, wr2, fmaf(xv.y, wr1, fmaf(xv.x, wr0, ar[j]))));
        }
    }
#pragma unroll
    for (int j = 0; j < NPW; ++j) {
        out0[(node0 + j) * KF + kf] = ai[j];
        root[(node0 + j) * KF + kf] = ar[j];
    }
}

// ---- per-stack deep GEMM: out[n,k,:] = in[n,k,:] @ w[k] ---------------------
template<int F, int K, int NPB>
__global__ void k_deep(const float* __restrict__ in,
                       const float* __restrict__ w,   // [K, F, F]
                       float* __restrict__ out, int n) {
    constexpr int KF = K * F;
    constexpr int WSZ = K * F * F;
    __shared__ float ws[WSZ];
    int t = threadIdx.x;
    for (int i = t; i < WSZ; i += blockDim.x) ws[i] = w[i];
    __syncthreads();
    int nn   = t / KF;
    int kf   = t % KF;
    int k    = kf / F;
    int h    = kf % F;
    int node = blockIdx.x * NPB + nn;
    if (node >= n) return;
    const float* irow = in + (long)node * KF + k * F;
    const float* wk = ws + k * F * F + h;
    float acc = 0.0f;
#pragma unroll
    for (int f = 0; f < F; ++f) acc = fmaf(irow[f], wk[f * F], acc);
    out[(long)node * KF + kf] = acc;
}

// ---- KF=64 gather: float2 lanes (32/node) + 2 nodes/thread = 4 chains/wave --
// MODE 1: relu store [n,64]; MODE 2: per-stack relu + mean over K=2 -> [n,32]
template<int MODE>
__global__ void k_gather64(const float* __restrict__ A, const int2* __restrict__ sedge,
                           const int* __restrict__ start, const float* __restrict__ root,
                           const float* __restrict__ bias, float* __restrict__ out,
                           int npairs) {
    int gid = blockIdx.x * blockDim.x + threadIdx.x;
    int q = gid >> 5, sub = gid & 31;
    if (q >= npairs) return;
    int na = 2 * q, nb = 2 * q + 1;
    float2 bi   = *(const float2*)&bias[2 * sub];
    float2 acca = *(const float2*)&root[(long)na * 64 + 2 * sub];
    float2 accb = *(const float2*)&root[(long)nb * 64 + 2 * sub];
    acca.x += bi.x; acca.y += bi.y;
    accb.x += bi.x; accb.y += bi.y;
    int ea = start[na], e1a = start[na + 1];
    int eb = start[nb], e1b = start[nb + 1];
    while (ea < e1a && eb < e1b) {
        int2 pa = sedge[ea]; int2 pb = sedge[eb];
        float2 va = *(const float2*)&A[(long)pa.x * 64 + 2 * sub];
        float2 vb = *(const float2*)&A[(long)pb.x * 64 + 2 * sub];
        float wa = __int_as_float(pa.y), wb = __int_as_float(pb.y);
        acca.x = fmaf(va.x, wa, acca.x); acca.y = fmaf(va.y, wa, acca.y);
        accb.x = fmaf(vb.x, wb, accb.x); accb.y = fmaf(vb.y, wb, accb.y);
        ++ea; ++eb;
    }
    for (; ea < e1a; ++ea) {
        int2 p = sedge[ea];
        float2 v = *(const float2*)&A[(long)p.x * 64 + 2 * sub];
        float w = __int_as_float(p.y);
        acca.x = fmaf(v.x, w, acca.x); acca.y = fmaf(v.y, w, acca.y);
    }
    for (; eb < e1b; ++eb) {
        int2 p = sedge[eb];
        float2 v = *(const float2*)&A[(long)p.x * 64 + 2 * sub];
        float w = __int_as_float(p.y);
        accb.x = fmaf(v.x, w, accb.x); accb.y = fmaf(v.y, w, accb.y);
    }
    if (MODE == 1) {
        *(float2*)&out[(long)na * 64 + 2 * sub] = make_float2(fmaxf(acca.x, 0.f), fmaxf(acca.y, 0.f));
        *(float2*)&out[(long)nb * 64 + 2 * sub] = make_float2(fmaxf(accb.x, 0.f), fmaxf(accb.y, 0.f));
    } else {
        float2 va = make_float2(fmaxf(acca.x, 0.f), fmaxf(acca.y, 0.f));
        float2 vb = make_float2(fmaxf(accb.x, 0.f), fmaxf(accb.y, 0.f));
        float2 oa = make_float2(__shfl_xor(va.x, 16), __shfl_xor(va.y, 16));
        float2 ob = make_float2(__shfl_xor(vb.x, 16), __shfl_xor(vb.y, 16));
        if (sub < 16) {
            *(float2*)&out[(long)na * 32 + 2 * sub] =
                make_float2(0.5f * (va.x + oa.x), 0.5f * (va.y + oa.y));
            *(float2*)&out[(long)nb * 32 + 2 * sub] =
                make_float2(0.5f * (vb.x + ob.x), 0.5f * (vb.y + ob.y));
        }
    }
}

// ---- KF=80 gather: scalar lanes, 2 nodes/thread (dual chain), plain store ---
__global__ void k_gather80(const float* __restrict__ A, const int2* __restrict__ sedge,
                           const int* __restrict__ start, const float* __restrict__ root,
                           const float* __restrict__ bias, float* __restrict__ out,
                           int npairs) {
    int gid = blockIdx.x * blockDim.x + threadIdx.x;
    int q = gid / 80, kf = gid % 80;
    if (q >= npairs) return;
    int na = 2 * q, nb = 2 * q + 1;
    float bi = bias[kf];
    float acca = root[(long)na * 80 + kf] + bi;
    float accb = root[(long)nb * 80 + kf] + bi;
    int ea = start[na], e1a = start[na + 1];
    int eb = start[nb], e1b = start[nb + 1];
    while (ea < e1a && eb < e1b) {
        int2 pa = sedge[ea]; int2 pb = sedge[eb];
        float va = A[(long)pa.x * 80 + kf];
        float vb = A[(long)pb.x * 80 + kf];
        acca = fmaf(va, __int_as_float(pa.y), acca);
        accb = fmaf(vb, __int_as_float(pb.y), accb);
        ++ea; ++eb;
    }
    for (; ea < e1a; ++ea) {
        int2 p = sedge[ea];
        acca = fmaf(A[(long)p.x * 80 + kf], __int_as_float(p.y), acca);
    }
    for (; eb < e1b; ++eb) {
        int2 p = sedge[eb];
        accb = fmaf(A[(long)p.x * 80 + kf], __int_as_float(p.y), accb);
    }
    out[(long)na * 80 + kf] = acca;
    out[(long)nb * 80 + kf] = accb;
}

// ---- conv2 epilogue: mean over K + row log_softmax (40 classes) ------------
__global__ void k_logsoftmax(const float* __restrict__ B, float* __restrict__ out, int n) {
    int gid  = blockIdx.x * blockDim.x + threadIdx.x;
    int wave = gid >> 6;
    int lane = gid & 63;
    if (wave >= n) return;
    float v = -INFINITY;
    if (lane < 40)
        v = 0.5f * (B[(long)wave * 80 + lane] + B[(long)wave * 80 + 40 + lane]);
    float m = v;
#pragma unroll
    for (int o = 32; o; o >>= 1) m = fmaxf(m, __shfl_xor(m, o));
    float ex = (lane < 40) ? expf(v - m) : 0.0f;
    float s = ex;
#pragma unroll
    for (int o = 32; o; o >>= 1) s += __shfl_xor(s, o);
    if (lane < 40) out[(long)wave * 40 + lane] = v - m - logf(s);
}

// ---------------------------------------------------------------------------
extern "C" void kernel_launch(void* const* d_in, const int* in_sizes, int n_in,
                              void* d_out, int out_size, void* d_ws, size_t ws_size,
                              hipStream_t stream) {
    const float* x       = (const float*)d_in[0];
    const int*   eidx    = (const int*)d_in[1];
    const float* w1_init = (const float*)d_in[2];
    const float* w1_deep = (const float*)d_in[3];
    const float* w1_root = (const float*)d_in[4];
    const float* b1      = (const float*)d_in[5];
    const float* w2_init = (const float*)d_in[6];
    const float* w2_deep = (const float*)d_in[7];
    const float* w2_root = (const float*)d_in[8];
    const float* b2      = (const float*)d_in[9];
    float* out = (float*)d_out;

    const int N = in_sizes[0] / 128;
    const int E = in_sizes[1] / 2;
    const int* row = eidx;
    const int* col = eidx + E;

    // workspace layout; start padded to N+2 ints so A stays 8B-aligned (float2)
    int2*  sedge  = (int2*)d_ws;                 // E
    int*   start  = (int*)(sedge + E);           // N+2 (padded)
    float* A      = (float*)(start + N + 2);     // N*80
    float* B      = A + (long)N * 80;            // N*80
    float* root   = B + (long)N * 80;            // N*80
    int*   deg_i  = (int*)(root + (long)N * 80); // N   (transient)
    int*   cursor = deg_i + N;                   // N   (transient)
    int*   bsum   = cursor + N;                  // 256 (transient)
    int*   bscan  = bsum + 256;                  // 256 (transient)
    float* dinv   = (float*)(bscan + 256);       // N   (transient)
    float* h      = B;                           // N*32, aliases B (safe: see order)

    const int BS = 256;
    auto cdiv = [](long a, long b) { return (int)((a + b - 1) / b); };
    const int NP = N / 2;   // node pairs (N even)

    // ---- CSC build: histogram -> scan -> bucket scatter ----
    hipMemsetAsync(deg_i, 0, (size_t)N * 4, stream);
    k_hist<<<cdiv(E, BS), BS, 0, stream>>>(col, deg_i, E);
    k_dinv<<<cdiv(N, BS), BS, 0, stream>>>(deg_i, dinv, N);
    k_scan1<<<256, 256, 0, stream>>>(deg_i, start, bsum, N);
    k_scan2<<<1, 256, 0, stream>>>(bsum, bscan);
    k_scan3<<<256, 256, 0, stream>>>(start, cursor, bscan, N);
    k_sort<<<cdiv(E, BS), BS, 0, stream>>>(row, col, dinv, cursor, sedge, E);

    // ---- conv1: 128 -> 32, K=2 (KF=64), relu ----
    // GPB=16 groups x NPW=4 nodes: block=1024, 64 nodes/block; LDS reads /4.
    k_gemm_in<128, 32, 2, 16, 4><<<cdiv(N, 64), 1024, 0, stream>>>(x, w1_init, w1_root, A, root, N);
    k_gather64<1><<<cdiv((long)NP * 32, BS), BS, 0, stream>>>(A, sedge, start, root, b1, B, NP);
    k_deep<32, 2, 16><<<cdiv(N, 16), 16 * 64, 0, stream>>>(B, w1_deep, A, N);
    k_gather64<2><<<cdiv((long)NP * 32, BS), BS, 0, stream>>>(A, sedge, start, root, b1, h, NP);

    // ---- conv2: 32 -> 40, K=2 (KF=80), no act ----
    k_gemm_in<32, 40, 2, 8, 4><<<cdiv(N, 32), 640, 0, stream>>>(h, w2_init, w2_root, A, root, N);
    k_gather80<<<cdiv((long)NP * 80, 320), 320, 0, stream>>>(A, sedge, start, root, b2, B, NP);
    k_deep<40, 2, 8><<<cdiv(N, 8), 8 * 80, 0, stream>>>(B, w2_deep, A, N);
    k_gather80<<<cdiv((long)NP * 80, 320), 320, 0, stream>>>(A, sedge, start, root, b2, B, NP);

    // ---- epilogue: mean over K + log_softmax ----
    k_logsoftmax<<<cdiv((long)N * 64, BS), BS, 0, stream>>>(B, out, N);
}

// Round 7
// 518.360 us; speedup vs baseline: 1.1595x; 1.1595x over previous
//
#include <hip/hip_runtime.h>
#include <math.h>

// ---------------------------------------------------------------------------
// ARMA GNN forward: gcn_norm -> ARMAConv(128->32,K=2,T=2,relu) -> relu ->
//                   ARMAConv(32->40,K=2,T=2) -> log_softmax
// CSC gather propagation; message buffer A stored in bf16 (halves gather
// traffic: the 1.9 TB/s LLC-path plateau was the round-6 bottleneck).
// ---------------------------------------------------------------------------

typedef unsigned short ushort_t;

__device__ inline ushort_t f2bf(float v) {           // RNE f32 -> bf16
    unsigned u = __float_as_uint(v);
    u += 0x7FFFu + ((u >> 16) & 1u);
    return (ushort_t)(u >> 16);
}
__device__ inline float2 unpack2(unsigned p) {       // 2 packed bf16 -> float2
    return make_float2(__uint_as_float(p << 16), __uint_as_float(p & 0xFFFF0000u));
}

__global__ void k_hist(const int* __restrict__ col, int* __restrict__ deg, int e) {
    int i = blockIdx.x * blockDim.x + threadIdx.x;
    if (i < e) atomicAdd(&deg[col[i]], 1);
}

__global__ void k_dinv(const int* __restrict__ deg, float* __restrict__ dinv, int n) {
    int i = blockIdx.x * blockDim.x + threadIdx.x;
    if (i < n) {
        int d = deg[i];
        dinv[i] = d > 0 ? rsqrtf((float)d) : 0.0f;
    }
}

__global__ void k_scan1(const int* __restrict__ deg, int* __restrict__ start,
                        int* __restrict__ bsum, int n) {
    __shared__ int s[256];
    int t = threadIdx.x, idx = blockIdx.x * 256 + t;
    int v = (idx < n) ? deg[idx] : 0;
    s[t] = v; __syncthreads();
    for (int o = 1; o < 256; o <<= 1) {
        int x = (t >= o) ? s[t - o] : 0;
        __syncthreads(); s[t] += x; __syncthreads();
    }
    if (idx <= n) start[idx] = s[t] - v;
    if (t == 255) bsum[blockIdx.x] = s[255];
}

__global__ void k_scan2(const int* __restrict__ bsum, int* __restrict__ bscan) {
    __shared__ int s[256];
    int t = threadIdx.x;
    int v = bsum[t]; s[t] = v; __syncthreads();
    for (int o = 1; o < 256; o <<= 1) {
        int x = (t >= o) ? s[t - o] : 0;
        __syncthreads(); s[t] += x; __syncthreads();
    }
    bscan[t] = s[t] - v;
}

__global__ void k_scan3(int* __restrict__ start, int* __restrict__ cursor,
                        const int* __restrict__ bscan, int n) {
    int idx = blockIdx.x * 256 + threadIdx.x;
    if (idx <= n) {
        int v = start[idx] + bscan[idx >> 8];
        start[idx] = v;
        if (idx < n) cursor[idx] = v;
    }
}

__global__ void k_sort(const int* __restrict__ row, const int* __restrict__ col,
                       const float* __restrict__ dinv, int* __restrict__ cursor,
                       int2* __restrict__ sedge, int e) {
    int i = blockIdx.x * blockDim.x + threadIdx.x;
    if (i < e) {
        int r = row[i], c = col[i];
        int pos = atomicAdd(&cursor[c], 1);
        sedge[pos] = make_int2(r, __float_as_int(dinv[r] * dinv[c]));
    }
}

// ---- fused init+root GEMM, NPW nodes/thread; out0 bf16, root f32 -----------
template<int F_IN, int F_OUT, int K, int GPB, int NPW>
__global__ void k_gemm_in(const float* __restrict__ x,
                          const float* __restrict__ w_init,
                          const float* __restrict__ w_root,
                          ushort_t* __restrict__ out0,
                          float* __restrict__ root,
                          int n) {
    constexpr int KF = K * F_OUT;
    constexpr int WSZ = K * F_IN * F_OUT;
    __shared__ float ws_i[WSZ];
    __shared__ float ws_r[WSZ];
    int t = threadIdx.x;
    for (int i = t; i < WSZ; i += blockDim.x) {
        ws_i[i] = w_init[i];
        ws_r[i] = w_root[i];
    }
    __syncthreads();
    int g  = t / KF;
    int kf = t % KF;
    int k  = kf / F_OUT;
    int h  = kf % F_OUT;
    long node0 = ((long)blockIdx.x * GPB + g) * NPW;
    if (node0 >= n) return;                 // n % NPW == 0
    const float* wip = ws_i + k * F_IN * F_OUT + h;
    const float* wrp = ws_r + k * F_IN * F_OUT + h;
    float ai[NPW], ar[NPW];
#pragma unroll
    for (int j = 0; j < NPW; ++j) { ai[j] = 0.0f; ar[j] = 0.0f; }
    for (int f = 0; f < F_IN; f += 4) {
        float wi0 = wip[(f + 0) * F_OUT], wi1 = wip[(f + 1) * F_OUT];
        float wi2 = wip[(f + 2) * F_OUT], wi3 = wip[(f + 3) * F_OUT];
        float wr0 = wrp[(f + 0) * F_OUT], wr1 = wrp[(f + 1) * F_OUT];
        float wr2 = wrp[(f + 2) * F_OUT], wr3 = wrp[(f + 3) * F_OUT];
#pragma unroll
        for (int j = 0; j < NPW; ++j) {
            float4 xv = *(const float4*)&x[(node0 + j) * F_IN + f];
            ai[j] = fmaf(xv.w, wi3, fmaf(xv.z, wi2, fmaf(xv.y, wi1, fmaf(xv.x, wi0, ai[j]))));
            ar[j] = fmaf(xv.w, wr3, fmaf(xv.z, wr2, fmaf(xv.y, wr1, fmaf(xv.x, wr0, ar[j]))));
        }
    }
#pragma unroll
    for (int j = 0; j < NPW; ++j) {
        out0[(node0 + j) * KF + kf] = f2bf(ai[j]);
        root[(node0 + j) * KF + kf] = ar[j];
    }
}

// ---- per-stack deep GEMM, NPW nodes/thread; in f32, out bf16 ---------------
template<int F, int K, int GPB, int NPW>
__global__ void k_deep(const float* __restrict__ in,
                       const float* __restrict__ w,   // [K, F, F]
                       ushort_t* __restrict__ out, int n) {
    constexpr int KF = K * F;
    constexpr int WSZ = K * F * F;
    __shared__ float ws[WSZ];
    int t = threadIdx.x;
    for (int i = t; i < WSZ; i += blockDim.x) ws[i] = w[i];
    __syncthreads();
    int g  = t / KF;
    int kf = t % KF;
    int k  = kf / F;
    int h  = kf % F;
    long node0 = ((long)blockIdx.x * GPB + g) * NPW;
    if (node0 >= n) return;
    const float* wk = ws + k * F * F + h;
    float acc[NPW];
#pragma unroll
    for (int j = 0; j < NPW; ++j) acc[j] = 0.0f;
    for (int f = 0; f < F; f += 4) {
        float w0 = wk[(f + 0) * F], w1 = wk[(f + 1) * F];
        float w2 = wk[(f + 2) * F], w3 = wk[(f + 3) * F];
#pragma unroll
        for (int j = 0; j < NPW; ++j) {
            float4 xv = *(const float4*)&in[(node0 + j) * KF + k * F + f];
            acc[j] = fmaf(xv.w, w3, fmaf(xv.z, w2, fmaf(xv.y, w1, fmaf(xv.x, w0, acc[j]))));
        }
    }
#pragma unroll
    for (int j = 0; j < NPW; ++j) out[(node0 + j) * KF + kf] = f2bf(acc[j]);
}

// ---- KF=64 gather: 32 lanes/node, 2 bf16 feats per lane, 2 nodes/thread ----
// MODE 1: relu store [n,64] f32; MODE 2: per-stack relu + mean K=2 -> [n,32]
template<int MODE>
__global__ void k_gather64(const ushort_t* __restrict__ A, const int2* __restrict__ sedge,
                           const int* __restrict__ start, const float* __restrict__ root,
                           const float* __restrict__ bias, float* __restrict__ out,
                           int npairs) {
    const unsigned* A32 = (const unsigned*)A;
    int gid = blockIdx.x * blockDim.x + threadIdx.x;
    int q = gid >> 5, sub = gid & 31;
    if (q >= npairs) return;
    int na = 2 * q, nb = 2 * q + 1;
    float2 bi   = *(const float2*)&bias[2 * sub];
    float2 acca = *(const float2*)&root[(long)na * 64 + 2 * sub];
    float2 accb = *(const float2*)&root[(long)nb * 64 + 2 * sub];
    acca.x += bi.x; acca.y += bi.y;
    accb.x += bi.x; accb.y += bi.y;
    int ea = start[na], e1a = start[na + 1];
    int eb = start[nb], e1b = start[nb + 1];
    while (ea < e1a && eb < e1b) {
        int2 pa = sedge[ea]; int2 pb = sedge[eb];
        float2 va = unpack2(A32[(long)pa.x * 32 + sub]);
        float2 vb = unpack2(A32[(long)pb.x * 32 + sub]);
        float wa = __int_as_float(pa.y), wb = __int_as_float(pb.y);
        acca.x = fmaf(va.x, wa, acca.x); acca.y = fmaf(va.y, wa, acca.y);
        accb.x = fmaf(vb.x, wb, accb.x); accb.y = fmaf(vb.y, wb, accb.y);
        ++ea; ++eb;
    }
    for (; ea < e1a; ++ea) {
        int2 p = sedge[ea];
        float2 v = unpack2(A32[(long)p.x * 32 + sub]);
        float w = __int_as_float(p.y);
        acca.x = fmaf(v.x, w, acca.x); acca.y = fmaf(v.y, w, acca.y);
    }
    for (; eb < e1b; ++eb) {
        int2 p = sedge[eb];
        float2 v = unpack2(A32[(long)p.x * 32 + sub]);
        float w = __int_as_float(p.y);
        accb.x = fmaf(v.x, w, accb.x); accb.y = fmaf(v.y, w, accb.y);
    }
    if (MODE == 1) {
        *(float2*)&out[(long)na * 64 + 2 * sub] = make_float2(fmaxf(acca.x, 0.f), fmaxf(acca.y, 0.f));
        *(float2*)&out[(long)nb * 64 + 2 * sub] = make_float2(fmaxf(accb.x, 0.f), fmaxf(accb.y, 0.f));
    } else {
        float2 va = make_float2(fmaxf(acca.x, 0.f), fmaxf(acca.y, 0.f));
        float2 vb = make_float2(fmaxf(accb.x, 0.f), fmaxf(accb.y, 0.f));
        float2 oa = make_float2(__shfl_xor(va.x, 16), __shfl_xor(va.y, 16));
        float2 ob = make_float2(__shfl_xor(vb.x, 16), __shfl_xor(vb.y, 16));
        if (sub < 16) {
            *(float2*)&out[(long)na * 32 + 2 * sub] =
                make_float2(0.5f * (va.x + oa.x), 0.5f * (va.y + oa.y));
            *(float2*)&out[(long)nb * 32 + 2 * sub] =
                make_float2(0.5f * (vb.x + ob.x), 0.5f * (vb.y + ob.y));
        }
    }
}

// ---- KF=80 gather: 40 lanes/node, 2 bf16 feats per lane, 2 nodes/thread ----
__global__ void k_gather80(const ushort_t* __restrict__ A, const int2* __restrict__ sedge,
                           const int* __restrict__ start, const float* __restrict__ root,
                           const float* __restrict__ bias, float* __restrict__ out,
                           int npairs) {
    const unsigned* A32 = (const unsigned*)A;
    int gid = blockIdx.x * blockDim.x + threadIdx.x;
    int q = gid / 40, f2 = gid % 40;
    if (q >= npairs) return;
    int na = 2 * q, nb = 2 * q + 1;
    float2 bi   = *(const float2*)&bias[2 * f2];
    float2 acca = *(const float2*)&root[(long)na * 80 + 2 * f2];
    float2 accb = *(const float2*)&root[(long)nb * 80 + 2 * f2];
    acca.x += bi.x; acca.y += bi.y;
    accb.x += bi.x; accb.y += bi.y;
    int ea = start[na], e1a = start[na + 1];
    int eb = start[nb], e1b = start[nb + 1];
    while (ea < e1a && eb < e1b) {
        int2 pa = sedge[ea]; int2 pb = sedge[eb];
        float2 va = unpack2(A32[(long)pa.x * 40 + f2]);
        float2 vb = unpack2(A32[(long)pb.x * 40 + f2]);
        float wa = __int_as_float(pa.y), wb = __int_as_float(pb.y);
        acca.x = fmaf(va.x, wa, acca.x); acca.y = fmaf(va.y, wa, acca.y);
        accb.x = fmaf(vb.x, wb, accb.x); accb.y = fmaf(vb.y, wb, accb.y);
        ++ea; ++eb;
    }
    for (; ea < e1a; ++ea) {
        int2 p = sedge[ea];
        float2 v = unpack2(A32[(long)p.x * 40 + f2]);
        float w = __int_as_float(p.y);
        acca.x = fmaf(v.x, w, acca.x); acca.y = fmaf(v.y, w, acca.y);
    }
    for (; eb < e1b; ++eb) {
        int2 p = sedge[eb];
        float2 v = unpack2(A32[(long)p.x * 40 + f2]);
        float w = __int_as_float(p.y);
        accb.x = fmaf(v.x, w, accb.x); accb.y = fmaf(v.y, w, accb.y);
    }
    *(float2*)&out[(long)na * 80 + 2 * f2] = acca;
    *(float2*)&out[(long)nb * 80 + 2 * f2] = accb;
}

// ---- conv2 epilogue: mean over K + row log_softmax (40 classes) ------------
__global__ void k_logsoftmax(const float* __restrict__ B, float* __restrict__ out, int n) {
    int gid  = blockIdx.x * blockDim.x + threadIdx.x;
    int wave = gid >> 6;
    int lane = gid & 63;
    if (wave >= n) return;
    float v = -INFINITY;
    if (lane < 40)
        v = 0.5f * (B[(long)wave * 80 + lane] + B[(long)wave * 80 + 40 + lane]);
    float m = v;
#pragma unroll
    for (int o = 32; o; o >>= 1) m = fmaxf(m, __shfl_xor(m, o));
    float ex = (lane < 40) ? expf(v - m) : 0.0f;
    float s = ex;
#pragma unroll
    for (int o = 32; o; o >>= 1) s += __shfl_xor(s, o);
    if (lane < 40) out[(long)wave * 40 + lane] = v - m - logf(s);
}

// ---------------------------------------------------------------------------
extern "C" void kernel_launch(void* const* d_in, const int* in_sizes, int n_in,
                              void* d_out, int out_size, void* d_ws, size_t ws_size,
                              hipStream_t stream) {
    const float* x       = (const float*)d_in[0];
    const int*   eidx    = (const int*)d_in[1];
    const float* w1_init = (const float*)d_in[2];
    const float* w1_deep = (const float*)d_in[3];
    const float* w1_root = (const float*)d_in[4];
    const float* b1      = (const float*)d_in[5];
    const float* w2_init = (const float*)d_in[6];
    const float* w2_deep = (const float*)d_in[7];
    const float* w2_root = (const float*)d_in[8];
    const float* b2      = (const float*)d_in[9];
    float* out = (float*)d_out;

    const int N = in_sizes[0] / 128;
    const int E = in_sizes[1] / 2;
    const int* row = eidx;
    const int* col = eidx + E;

    // workspace layout (start padded to N+4 ints to keep B/root 16B-aligned)
    int2*     sedge  = (int2*)d_ws;                  // E
    int*      start  = (int*)(sedge + E);            // N+4 (padded)
    ushort_t* A      = (ushort_t*)(start + N + 4);   // N*80 bf16
    float*    B      = (float*)(A + (long)N * 80);   // N*80 f32
    float*    root   = B + (long)N * 80;             // N*80 f32
    int*      deg_i  = (int*)(root + (long)N * 80);  // N   (transient)
    int*      cursor = deg_i + N;                    // N   (transient)
    int*      bsum   = cursor + N;                   // 256 (transient)
    int*      bscan  = bsum + 256;                   // 256 (transient)
    float*    dinv   = (float*)(bscan + 256);        // N   (transient)
    float*    h      = B;                            // N*32 f32, aliases B

    const int BS = 256;
    auto cdiv = [](long a, long b) { return (int)((a + b - 1) / b); };
    const int NP = N / 2;   // node pairs (N even)

    // ---- CSC build: histogram -> scan -> bucket scatter ----
    hipMemsetAsync(deg_i, 0, (size_t)N * 4, stream);
    k_hist<<<cdiv(E, BS), BS, 0, stream>>>(col, deg_i, E);
    k_dinv<<<cdiv(N, BS), BS, 0, stream>>>(deg_i, dinv, N);
    k_scan1<<<256, 256, 0, stream>>>(deg_i, start, bsum, N);
    k_scan2<<<1, 256, 0, stream>>>(bsum, bscan);
    k_scan3<<<256, 256, 0, stream>>>(start, cursor, bscan, N);
    k_sort<<<cdiv(E, BS), BS, 0, stream>>>(row, col, dinv, cursor, sedge, E);

    // ---- conv1: 128 -> 32, K=2 (KF=64), relu ----
    k_gemm_in<128, 32, 2, 16, 4><<<cdiv(N, 64), 1024, 0, stream>>>(x, w1_init, w1_root, A, root, N);
    k_gather64<1><<<cdiv((long)NP * 32, BS), BS, 0, stream>>>(A, sedge, start, root, b1, B, NP);
    k_deep<32, 2, 16, 4><<<cdiv(N, 64), 1024, 0, stream>>>(B, w1_deep, A, N);
    k_gather64<2><<<cdiv((long)NP * 32, BS), BS, 0, stream>>>(A, sedge, start, root, b1, h, NP);

    // ---- conv2: 32 -> 40, K=2 (KF=80), no act ----
    k_gemm_in<32, 40, 2, 8, 4><<<cdiv(N, 32), 640, 0, stream>>>(h, w2_init, w2_root, A, root, N);
    k_gather80<<<cdiv((long)NP * 40, 320), 320, 0, stream>>>(A, sedge, start, root, b2, B, NP);
    k_deep<40, 2, 8, 4><<<cdiv(N, 32), 640, 0, stream>>>(B, w2_deep, A, N);
    k_gather80<<<cdiv((long)NP * 40, 320), 320, 0, stream>>>(A, sedge, start, root, b2, B, NP);

    // ---- epilogue: mean over K + log_softmax ----
    k_logsoftmax<<<cdiv((long)N * 64, BS), BS, 0, stream>>>(B, out, N);
}

// Round 8
// 440.980 us; speedup vs baseline: 1.3629x; 1.1755x over previous
//
#include <hip/hip_runtime.h>
#include <math.h>

// ---------------------------------------------------------------------------
// ARMA GNN forward: gcn_norm -> ARMAConv(128->32,K=2,T=2,relu) -> relu ->
//                   ARMAConv(32->40,K=2,T=2) -> log_softmax
// CSC gather propagation (bf16 messages); ALL dense GEMMs on MFMA
// (mfma_f32_16x16x32_bf16, weights pre-transposed bf16, L1-resident).
// ---------------------------------------------------------------------------

typedef unsigned short ushort_t;
typedef __attribute__((ext_vector_type(8))) short  short8v;   // 8 bf16 (4 VGPR)
typedef __attribute__((ext_vector_type(4))) float  float4v;   // C/D frag

__device__ inline ushort_t f2bf(float v) {           // RNE f32 -> bf16
    unsigned u = __float_as_uint(v);
    u += 0x7FFFu + ((u >> 16) & 1u);
    return (ushort_t)(u >> 16);
}
__device__ inline float2 unpack2(unsigned p) {       // 2 packed bf16 -> float2
    return make_float2(__uint_as_float(p << 16), __uint_as_float(p & 0xFFFF0000u));
}

// ---- CSC build ------------------------------------------------------------
__global__ void k_hist(const int* __restrict__ col, int* __restrict__ deg, int e) {
    int i = blockIdx.x * blockDim.x + threadIdx.x;
    if (i < e) atomicAdd(&deg[col[i]], 1);
}

__global__ void k_dinv(const int* __restrict__ deg, float* __restrict__ dinv, int n) {
    int i = blockIdx.x * blockDim.x + threadIdx.x;
    if (i < n) {
        int d = deg[i];
        dinv[i] = d > 0 ? rsqrtf((float)d) : 0.0f;
    }
}

__global__ void k_scan1(const int* __restrict__ deg, int* __restrict__ start,
                        int* __restrict__ bsum, int n) {
    __shared__ int s[256];
    int t = threadIdx.x, idx = blockIdx.x * 256 + t;
    int v = (idx < n) ? deg[idx] : 0;
    s[t] = v; __syncthreads();
    for (int o = 1; o < 256; o <<= 1) {
        int x = (t >= o) ? s[t - o] : 0;
        __syncthreads(); s[t] += x; __syncthreads();
    }
    if (idx <= n) start[idx] = s[t] - v;
    if (t == 255) bsum[blockIdx.x] = s[255];
}

__global__ void k_scan2(const int* __restrict__ bsum, int* __restrict__ bscan) {
    __shared__ int s[256];
    int t = threadIdx.x;
    int v = bsum[t]; s[t] = v; __syncthreads();
    for (int o = 1; o < 256; o <<= 1) {
        int x = (t >= o) ? s[t - o] : 0;
        __syncthreads(); s[t] += x; __syncthreads();
    }
    bscan[t] = s[t] - v;
}

__global__ void k_scan3(int* __restrict__ start, int* __restrict__ cursor,
                        const int* __restrict__ bscan, int n) {
    int idx = blockIdx.x * 256 + threadIdx.x;
    if (idx <= n) {
        int v = start[idx] + bscan[idx >> 8];
        start[idx] = v;
        if (idx < n) cursor[idx] = v;
    }
}

__global__ void k_sort(const int* __restrict__ row, const int* __restrict__ col,
                       const float* __restrict__ dinv, int* __restrict__ cursor,
                       int2* __restrict__ sedge, int e) {
    int i = blockIdx.x * blockDim.x + threadIdx.x;
    if (i < e) {
        int r = row[i], c = col[i];
        int pos = atomicAdd(&cursor[c], 1);
        sedge[pos] = make_int2(r, __float_as_int(dinv[r] * dinv[c]));
    }
}

// ---- weight prep: Wt[col][k] bf16, col = concat(init k*H+h, root k*H+h) ----
__global__ void k_wprep(const float* __restrict__ wi, const float* __restrict__ wr,
                        ushort_t* __restrict__ Wt, int K, int F, int H) {
    int idx = blockIdx.x * blockDim.x + threadIdx.x;
    int tot = 2 * K * H * F;
    if (idx >= tot) return;
    int f = idx % F, colx = idx / F;
    int KH = K * H;
    const float* src = (colx < KH) ? wi : wr;
    int c = (colx < KH) ? colx : colx - KH;
    int k = c / H, h = c % H;
    Wt[idx] = f2bf(src[((long)k * F + f) * H + h]);
}

// block-diagonal deep weights: Wt[col= k*F+h][kin (padded to FPAD)]
__global__ void k_wprep_diag(const float* __restrict__ w, ushort_t* __restrict__ Wt,
                             int K, int F, int FPAD) {
    int idx = blockIdx.x * blockDim.x + threadIdx.x;
    int tot = K * F * FPAD;
    if (idx >= tot) return;
    int kin = idx % FPAD, colx = idx / FPAD;
    int k = colx / F, h = colx % F;
    float v = 0.0f;
    if (kin < K * F) {
        int kp = kin / F, f = kin % F;
        if (kp == k) v = w[((long)k * F + f) * F + h];
    }
    Wt[idx] = f2bf(v);
}

// ---- MFMA GEMM: C[n, NCOLT*16] = X[n, FIN]_f32 @ Wt^T ----------------------
// Wt is [NCOLT*16][FPAD] bf16 (row = out col, contiguous k). One wave per
// 16-row M-tile. SPLIT: cols [0,KF0) -> out0 bf16, [KF0,2*KF0) -> root f32;
// else all KF0==NCOLT*16 cols -> out0 bf16.
// Requires n % 16 == 0 (N=50000). k indices >= FIN read past the row (in-
// bounds of the buffer) and are multiplied by zero weights.
template<int FIN, int FPAD, int NCOLT, int KF0, bool SPLIT>
__global__ void k_mfma_gemm(const float* __restrict__ X,
                            const ushort_t* __restrict__ Wt,
                            ushort_t* __restrict__ out0,
                            float* __restrict__ root,
                            int n) {
    constexpr int KSTEPS = FPAD / 32;
    int wid  = (blockIdx.x * blockDim.x + threadIdx.x) >> 6;
    int lane = threadIdx.x & 63;
    int m0 = wid * 16;
    if (m0 >= n) return;
    int r = lane & 15, g = lane >> 4;        // A row / D col = r ; k-group = g
    float4v acc[NCOLT];
#pragma unroll
    for (int c = 0; c < NCOLT; ++c) acc[c] = (float4v){0.f, 0.f, 0.f, 0.f};
#pragma unroll
    for (int ks = 0; ks < KSTEPS; ++ks) {
        int kb = ks * 32 + g * 8;
        const float* xr = X + (long)(m0 + r) * FIN + kb;
        float4 x0 = *(const float4*)xr;
        float4 x1 = *(const float4*)(xr + 4);
        short8v af;
        af[0] = (short)f2bf(x0.x); af[1] = (short)f2bf(x0.y);
        af[2] = (short)f2bf(x0.z); af[3] = (short)f2bf(x0.w);
        af[4] = (short)f2bf(x1.x); af[5] = (short)f2bf(x1.y);
        af[6] = (short)f2bf(x1.z); af[7] = (short)f2bf(x1.w);
#pragma unroll
        for (int c = 0; c < NCOLT; ++c) {
            short8v bf = *(const short8v*)&Wt[(long)(c * 16 + r) * FPAD + kb];
            acc[c] = __builtin_amdgcn_mfma_f32_16x16x32_bf16(af, bf, acc[c], 0, 0, 0);
        }
    }
#pragma unroll
    for (int c = 0; c < NCOLT; ++c) {
        int colx = c * 16 + r;
#pragma unroll
        for (int i = 0; i < 4; ++i) {
            long node = m0 + g * 4 + i;
            if (!SPLIT || colx < KF0)
                out0[node * KF0 + colx] = f2bf(acc[c][i]);
            else
                root[node * KF0 + (colx - KF0)] = acc[c][i];
        }
    }
}

// ---- KF=64 gather: 32 lanes/node, 2 bf16 feats per lane, 2 nodes/thread ----
template<int MODE>
__global__ void k_gather64(const ushort_t* __restrict__ A, const int2* __restrict__ sedge,
                           const int* __restrict__ start, const float* __restrict__ root,
                           const float* __restrict__ bias, float* __restrict__ out,
                           int npairs) {
    const unsigned* A32 = (const unsigned*)A;
    int gid = blockIdx.x * blockDim.x + threadIdx.x;
    int q = gid >> 5, sub = gid & 31;
    if (q >= npairs) return;
    int na = 2 * q, nb = 2 * q + 1;
    float2 bi   = *(const float2*)&bias[2 * sub];
    float2 acca = *(const float2*)&root[(long)na * 64 + 2 * sub];
    float2 accb = *(const float2*)&root[(long)nb * 64 + 2 * sub];
    acca.x += bi.x; acca.y += bi.y;
    accb.x += bi.x; accb.y += bi.y;
    int ea = start[na], e1a = start[na + 1];
    int eb = start[nb], e1b = start[nb + 1];
    while (ea < e1a && eb < e1b) {
        int2 pa = sedge[ea]; int2 pb = sedge[eb];
        float2 va = unpack2(A32[(long)pa.x * 32 + sub]);
        float2 vb = unpack2(A32[(long)pb.x * 32 + sub]);
        float wa = __int_as_float(pa.y), wb = __int_as_float(pb.y);
        acca.x = fmaf(va.x, wa, acca.x); acca.y = fmaf(va.y, wa, acca.y);
        accb.x = fmaf(vb.x, wb, accb.x); accb.y = fmaf(vb.y, wb, accb.y);
        ++ea; ++eb;
    }
    for (; ea < e1a; ++ea) {
        int2 p = sedge[ea];
        float2 v = unpack2(A32[(long)p.x * 32 + sub]);
        float w = __int_as_float(p.y);
        acca.x = fmaf(v.x, w, acca.x); acca.y = fmaf(v.y, w, acca.y);
    }
    for (; eb < e1b; ++eb) {
        int2 p = sedge[eb];
        float2 v = unpack2(A32[(long)p.x * 32 + sub]);
        float w = __int_as_float(p.y);
        accb.x = fmaf(v.x, w, accb.x); accb.y = fmaf(v.y, w, accb.y);
    }
    if (MODE == 1) {
        *(float2*)&out[(long)na * 64 + 2 * sub] = make_float2(fmaxf(acca.x, 0.f), fmaxf(acca.y, 0.f));
        *(float2*)&out[(long)nb * 64 + 2 * sub] = make_float2(fmaxf(accb.x, 0.f), fmaxf(accb.y, 0.f));
    } else {
        float2 va = make_float2(fmaxf(acca.x, 0.f), fmaxf(acca.y, 0.f));
        float2 vb = make_float2(fmaxf(accb.x, 0.f), fmaxf(accb.y, 0.f));
        float2 oa = make_float2(__shfl_xor(va.x, 16), __shfl_xor(va.y, 16));
        float2 ob = make_float2(__shfl_xor(vb.x, 16), __shfl_xor(vb.y, 16));
        if (sub < 16) {
            *(float2*)&out[(long)na * 32 + 2 * sub] =
                make_float2(0.5f * (va.x + oa.x), 0.5f * (va.y + oa.y));
            *(float2*)&out[(long)nb * 32 + 2 * sub] =
                make_float2(0.5f * (vb.x + ob.x), 0.5f * (vb.y + ob.y));
        }
    }
}

// ---- KF=80 gather: 40 lanes/node, 2 bf16 feats per lane, 2 nodes/thread ----
__global__ void k_gather80(const ushort_t* __restrict__ A, const int2* __restrict__ sedge,
                           const int* __restrict__ start, const float* __restrict__ root,
                           const float* __restrict__ bias, float* __restrict__ out,
                           int npairs) {
    const unsigned* A32 = (const unsigned*)A;
    int gid = blockIdx.x * blockDim.x + threadIdx.x;
    int q = gid / 40, f2 = gid % 40;
    if (q >= npairs) return;
    int na = 2 * q, nb = 2 * q + 1;
    float2 bi   = *(const float2*)&bias[2 * f2];
    float2 acca = *(const float2*)&root[(long)na * 80 + 2 * f2];
    float2 accb = *(const float2*)&root[(long)nb * 80 + 2 * f2];
    acca.x += bi.x; acca.y += bi.y;
    accb.x += bi.x; accb.y += bi.y;
    int ea = start[na], e1a = start[na + 1];
    int eb = start[nb], e1b = start[nb + 1];
    while (ea < e1a && eb < e1b) {
        int2 pa = sedge[ea]; int2 pb = sedge[eb];
        float2 va = unpack2(A32[(long)pa.x * 40 + f2]);
        float2 vb = unpack2(A32[(long)pb.x * 40 + f2]);
        float wa = __int_as_float(pa.y), wb = __int_as_float(pb.y);
        acca.x = fmaf(va.x, wa, acca.x); acca.y = fmaf(va.y, wa, acca.y);
        accb.x = fmaf(vb.x, wb, accb.x); accb.y = fmaf(vb.y, wb, accb.y);
        ++ea; ++eb;
    }
    for (; ea < e1a; ++ea) {
        int2 p = sedge[ea];
        float2 v = unpack2(A32[(long)p.x * 40 + f2]);
        float w = __int_as_float(p.y);
        acca.x = fmaf(v.x, w, acca.x); acca.y = fmaf(v.y, w, acca.y);
    }
    for (; eb < e1b; ++eb) {
        int2 p = sedge[eb];
        float2 v = unpack2(A32[(long)p.x * 40 + f2]);
        float w = __int_as_float(p.y);
        accb.x = fmaf(v.x, w, accb.x); accb.y = fmaf(v.y, w, accb.y);
    }
    *(float2*)&out[(long)na * 80 + 2 * f2] = acca;
    *(float2*)&out[(long)nb * 80 + 2 * f2] = accb;
}

// ---- conv2 epilogue: mean over K + row log_softmax (40 classes) ------------
__global__ void k_logsoftmax(const float* __restrict__ B, float* __restrict__ out, int n) {
    int gid  = blockIdx.x * blockDim.x + threadIdx.x;
    int wave = gid >> 6;
    int lane = gid & 63;
    if (wave >= n) return;
    float v = -INFINITY;
    if (lane < 40)
        v = 0.5f * (B[(long)wave * 80 + lane] + B[(long)wave * 80 + 40 + lane]);
    float m = v;
#pragma unroll
    for (int o = 32; o; o >>= 1) m = fmaxf(m, __shfl_xor(m, o));
    float ex = (lane < 40) ? expf(v - m) : 0.0f;
    float s = ex;
#pragma unroll
    for (int o = 32; o; o >>= 1) s += __shfl_xor(s, o);
    if (lane < 40) out[(long)wave * 40 + lane] = v - m - logf(s);
}

// ---------------------------------------------------------------------------
extern "C" void kernel_launch(void* const* d_in, const int* in_sizes, int n_in,
                              void* d_out, int out_size, void* d_ws, size_t ws_size,
                              hipStream_t stream) {
    const float* x       = (const float*)d_in[0];
    const int*   eidx    = (const int*)d_in[1];
    const float* w1_init = (const float*)d_in[2];
    const float* w1_deep = (const float*)d_in[3];
    const float* w1_root = (const float*)d_in[4];
    const float* b1      = (const float*)d_in[5];
    const float* w2_init = (const float*)d_in[6];
    const float* w2_deep = (const float*)d_in[7];
    const float* w2_root = (const float*)d_in[8];
    const float* b2      = (const float*)d_in[9];
    float* out = (float*)d_out;

    const int N = in_sizes[0] / 128;
    const int E = in_sizes[1] / 2;
    const int* row = eidx;
    const int* col = eidx + E;

    // workspace layout
    int2*     sedge  = (int2*)d_ws;                   // E
    int*      start  = (int*)(sedge + E);             // N+4 (padded for align)
    ushort_t* A      = (ushort_t*)(start + N + 4);    // N*80 bf16
    float*    B      = (float*)(A + (long)N * 80);    // N*80 f32
    float*    root   = B + (long)N * 80;              // N*80 f32
    ushort_t* Wt1    = (ushort_t*)(root + (long)N * 80); // 128*128 bf16
    ushort_t* Wt2    = Wt1 + 128 * 128;               // 160*32
    ushort_t* Wtd1   = Wt2 + 160 * 32;                // 64*64
    ushort_t* Wtd2   = Wtd1 + 64 * 64;                // 80*96
    int*      deg_i  = (int*)(Wtd2 + 80 * 96);        // N   (transient)
    int*      cursor = deg_i + N;                     // N   (transient)
    int*      bsum   = cursor + N;                    // 256 (transient)
    int*      bscan  = bsum + 256;                    // 256 (transient)
    float*    dinv   = (float*)(bscan + 256);         // N   (transient)
    float*    h      = B;                             // N*32 f32, aliases B

    const int BS = 256;
    auto cdiv = [](long a, long b) { return (int)((a + b - 1) / b); };
    const int NP = N / 2;          // node pairs (N even)
    const int MT = cdiv(N, 16);    // M-tiles (N % 16 == 0)

    // ---- CSC build + weight prep ----
    hipMemsetAsync(deg_i, 0, (size_t)N * 4, stream);
    k_hist<<<cdiv(E, BS), BS, 0, stream>>>(col, deg_i, E);
    k_dinv<<<cdiv(N, BS), BS, 0, stream>>>(deg_i, dinv, N);
    k_scan1<<<256, 256, 0, stream>>>(deg_i, start, bsum, N);
    k_scan2<<<1, 256, 0, stream>>>(bsum, bscan);
    k_scan3<<<256, 256, 0, stream>>>(start, cursor, bscan, N);
    k_sort<<<cdiv(E, BS), BS, 0, stream>>>(row, col, dinv, cursor, sedge, E);
    k_wprep<<<cdiv(2 * 2 * 32 * 128, BS), BS, 0, stream>>>(w1_init, w1_root, Wt1, 2, 128, 32);
    k_wprep<<<cdiv(2 * 2 * 40 * 32, BS), BS, 0, stream>>>(w2_init, w2_root, Wt2, 2, 32, 40);
    k_wprep_diag<<<cdiv(64 * 64, BS), BS, 0, stream>>>(w1_deep, Wtd1, 2, 32, 64);
    k_wprep_diag<<<cdiv(80 * 96, BS), BS, 0, stream>>>(w2_deep, Wtd2, 2, 40, 96);

    // ---- conv1: 128 -> 32, K=2 (KF=64), relu ----
    k_mfma_gemm<128, 128, 8, 64, true><<<cdiv(MT, 4), 256, 0, stream>>>(x, Wt1, A, root, N);
    k_gather64<1><<<cdiv((long)NP * 32, BS), BS, 0, stream>>>(A, sedge, start, root, b1, B, NP);
    k_mfma_gemm<64, 64, 4, 64, false><<<cdiv(MT, 4), 256, 0, stream>>>(B, Wtd1, A, nullptr, N);
    k_gather64<2><<<cdiv((long)NP * 32, BS), BS, 0, stream>>>(A, sedge, start, root, b1, h, NP);

    // ---- conv2: 32 -> 40, K=2 (KF=80), no act ----
    k_mfma_gemm<32, 32, 10, 80, true><<<cdiv(MT, 4), 256, 0, stream>>>(h, Wt2, A, root, N);
    k_gather80<<<cdiv((long)NP * 40, 320), 320, 0, stream>>>(A, sedge, start, root, b2, B, NP);
    k_mfma_gemm<80, 96, 5, 80, false><<<cdiv(MT, 4), 256, 0, stream>>>(B, Wtd2, A, nullptr, N);
    k_gather80<<<cdiv((long)NP * 40, 320), 320, 0, stream>>>(A, sedge, start, root, b2, B, NP);

    // ---- epilogue: mean over K + log_softmax ----
    k_logsoftmax<<<cdiv((long)N * 64, BS), BS, 0, stream>>>(B, out, N);
}